// Round 1
// baseline (2888.241 us; speedup 1.0000x reference)
//
#include <hip/hip_runtime.h>
#include <math.h>

// NMSLoss4: B=8 images, N=2048 proposals, G=64 gts.
// Inputs (setup_inputs order): gt_inds (unused), anchor_gt_inds (B*N i32),
// gt_bboxes (B*G*4 f32), proposal_list (B*N*5 f32). Output: 2 f32.

#define B_IMG 8
#define NN 2048
#define GG 64
#define THREADS 256
#define SLOTS (NN / THREADS)   // 8 proposals per thread
#define NMS_THR_F 0.5f
#define MIN_H 50.0f
#define EPSF 1e-6f

__device__ __forceinline__ float iou_pair(
    float ax1, float ay1, float ax2, float ay2,
    float bx1, float by1, float bx2, float by2) {
  // Matches bbox_overlaps: inter / (area_a + area_b - inter + 1e-10)
  float area_a = (ax2 - ax1) * (ay2 - ay1);
  float area_b = (bx2 - bx1) * (by2 - by1);
  float lx = fmaxf(ax1, bx1), ly = fmaxf(ay1, by1);
  float rx = fminf(ax2, bx2), ry = fminf(ay2, by2);
  float w = fmaxf(rx - lx, 0.0f), h = fmaxf(ry - ly, 0.0f);
  float inter = w * h;
  return inter / (area_a + area_b - inter + 1e-10f);
}

__global__ __launch_bounds__(THREADS) void nms_loss_img(
    const int* __restrict__ agti_all,
    const float* __restrict__ gtb_all,
    const float* __restrict__ prop_all,
    float* __restrict__ per_img) {
  const int b = blockIdx.x;
  const int tid = threadIdx.x;
  const int* agti = agti_all + b * NN;
  const float* gtb = gtb_all + b * GG * 4;
  const float* prop = prop_all + (size_t)b * NN * 5;

  __shared__ float sbx1[NN], sby1[NN], sbx2[NN], sby2[NN];
  __shared__ float ssc[NN], sgtpi[NN];
  __shared__ int sg[NN];
  __shared__ unsigned long long sbest[GG];   // per-gt best (score,idx) key
  __shared__ float sgt[GG * 4];
  __shared__ unsigned long long wkey[THREADS / 64];
  __shared__ int s_winner;
  __shared__ int s_count;

  if (tid < GG * 4) sgt[tid] = gtb[tid];
  if (tid < GG) sbest[tid] = 0ull;
  if (tid == 0) s_count = 0;
  __syncthreads();

  // Per-thread register state: 8 strided proposals.
  float rx1[SLOTS], ry1[SLOTS], rx2[SLOTS], ry2[SLOTS];
  unsigned long long rkey[SLOTS];  // 0 == inactive
  int poscnt = 0;
  #pragma unroll
  for (int k = 0; k < SLOTS; ++k) {
    int j = tid + k * THREADS;
    float x1 = prop[j * 5 + 0], y1 = prop[j * 5 + 1];
    float x2 = prop[j * 5 + 2], y2 = prop[j * 5 + 3];
    float sc = prop[j * 5 + 4];
    rx1[k] = x1; ry1[k] = y1; rx2[k] = x2; ry2[k] = y2;
    int a = agti[j];
    int g = a < 0 ? 0 : a;
    float gi = iou_pair(sgt[g * 4 + 0], sgt[g * 4 + 1], sgt[g * 4 + 2], sgt[g * 4 + 3],
                        x1, y1, x2, y2);
    sbx1[j] = x1; sby1[j] = y1; sbx2[j] = x2; sby2[j] = y2;
    ssc[j] = sc; sgtpi[j] = gi; sg[j] = a;
    // key: higher score wins; ties -> lower index (matches jnp.argmax).
    unsigned long long key =
        ((unsigned long long)__float_as_uint(sc) << 32) | (unsigned)(~(unsigned)j);
    if (a >= 0) {
      rkey[k] = key;
      ++poscnt;
      atomicMax(&sbest[a], key);
    } else {
      rkey[k] = 0ull;
    }
  }
  if (poscnt) atomicAdd(&s_count, poscnt);
  __syncthreads();

  const int init_count = s_count;

  // Thread-0 private scan state.
  unsigned long long seen = 0ull;
  float tp = 0.0f;
  int pc = 0;

  for (;;) {
    // ---- argmax over active scores ----
    unsigned long long kmax = 0ull;
    #pragma unroll
    for (int k = 0; k < SLOTS; ++k) kmax = rkey[k] > kmax ? rkey[k] : kmax;
    #pragma unroll
    for (int off = 32; off > 0; off >>= 1) {
      unsigned long long o = __shfl_xor(kmax, off, 64);
      kmax = o > kmax ? o : kmax;
    }
    if ((tid & 63) == 0) wkey[tid >> 6] = kmax;
    __syncthreads();
    if (tid == 0) {
      unsigned long long best = 0ull;
      for (int w = 0; w < THREADS / 64; ++w) best = wkey[w] > best ? wkey[w] : best;
      int i = -1;
      if (best != 0ull) {
        i = (int)(~(unsigned)(best & 0xffffffffull));
        // bookkeeping (scan-order dependent, serial by construction)
        int g = sg[i];                       // active => agti[i] >= 0
        bool seen_g = (seen >> g) & 1ull;
        float msi = fmaxf(sgtpi[i], EPSF);
        float pull = -logf(fminf(1.0f - NMS_THR_F + msi, 1.0f)) * ssc[i];
        bool has_rem = s_count >= 2;         // another active box besides i
        if (seen_g) { pc += 1; if (has_rem) tp += pull; }
        seen |= 1ull << g;
      }
      s_winner = i;
    }
    __syncthreads();
    const int i = s_winner;
    if (i < 0) break;
    const float bx1 = sbx1[i], by1 = sby1[i], bx2 = sbx2[i], by2 = sby2[i];
    int dead = 0;
    #pragma unroll
    for (int k = 0; k < SLOTS; ++k) {
      if (rkey[k] != 0ull) {
        int j = tid + k * THREADS;
        bool kill = (j == i) ||
            (iou_pair(rx1[k], ry1[k], rx2[k], ry2[k], bx1, by1, bx2, by2) > NMS_THR_F);
        if (kill) { rkey[k] = 0ull; ++dead; }
      }
    }
    if (dead) atomicSub(&s_count, dead);
    __syncthreads();
  }

  // ---- push term + finalize per image ----
  if (tid == 0) {
    float total_push = 0.0f;
    int push_cnt = 0;
    for (int g = 0; g < GG; ++g) {
      unsigned long long key = sbest[g];
      if (key == 0ull) continue;             // has_prop false
      float h = sgt[g * 4 + 3] - sgt[g * 4 + 1];
      bool sg_seen = (seen >> g) & 1ull;
      if (h >= MIN_H && !sg_seen) {
        int bestj = (int)(~(unsigned)(key & 0xffffffffull));
        total_push += 1.0f - sgtpi[bestj];   // gtp[g, best] == gtpi[best]
        ++push_cnt;
      }
    }
    float push_loss = 0.0f, pull_loss = 0.0f;
    if (init_count > 1) {
      pull_loss = tp / ((float)pc + EPSF);
      push_loss = total_push / ((float)push_cnt + EPSF);
    }
    per_img[b * 2 + 0] = push_loss;
    per_img[b * 2 + 1] = pull_loss;
  }
}

__global__ void nms_loss_final(const float* __restrict__ per_img,
                               float* __restrict__ out) {
  if (threadIdx.x == 0 && blockIdx.x == 0) {
    float sp = 0.0f, sl = 0.0f;
    for (int b = 0; b < B_IMG; ++b) {
      sp += per_img[b * 2 + 0];
      sl += per_img[b * 2 + 1];
    }
    out[0] = sp * (1.0f / B_IMG);  // mean(push) * PUSH_W
    out[1] = sl * (1.0f / B_IMG);  // mean(pull) * PULL_W
  }
}

extern "C" void kernel_launch(void* const* d_in, const int* in_sizes, int n_in,
                              void* d_out, int out_size, void* d_ws, size_t ws_size,
                              hipStream_t stream) {
  // d_in[0]=gt_inds (unused), d_in[1]=anchor_gt_inds, d_in[2]=gt_bboxes,
  // d_in[3]=proposal_list
  const int* agti = (const int*)d_in[1];
  const float* gtb = (const float*)d_in[2];
  const float* prop = (const float*)d_in[3];
  float* per_img = (float*)d_ws;  // B*2 floats

  nms_loss_img<<<B_IMG, THREADS, 0, stream>>>(agti, gtb, prop, per_img);
  nms_loss_final<<<1, 64, 0, stream>>>(per_img, (float*)d_out);
}

// Round 2
// 524.205 us; speedup vs baseline: 5.5098x; 5.5098x over previous
//
#include <hip/hip_runtime.h>
#include <math.h>

// NMSLoss4: B=8, N=2048, G=64. Sorted-order scan with precomputed sparse
// suppression lists. Inputs: gt_inds(unused), anchor_gt_inds(B*N i32),
// gt_bboxes(B*G*4 f32), proposal_list(B*N*5 f32). Output: 2 f32.

#define B_IMG 8
#define NN 2048
#define GG 64
#define NMS_T 0.5f
#define MIN_H 50.0f
#define EPSF 1e-6f
#define CAP 12

// ws layout per image (bytes)
#define OFF_X1 0
#define OFF_Y1 8192
#define OFF_X2 16384
#define OFF_Y2 24576
#define OFF_PULL 32768
#define OFF_GTPI 40960
#define OFF_AGTI 49152
#define OFF_CNT 57344
#define OFF_ENT 65536            // u16[2048*12] = 49152 B
#define OFF_NPOS 114688
#define IMG_STRIDE 114944
#define OFF_PERIMG ((size_t)B_IMG * IMG_STRIDE)

__device__ __forceinline__ float iou_pair(
    float ax1, float ay1, float ax2, float ay2,
    float bx1, float by1, float bx2, float by2) {
  float area_a = (ax2 - ax1) * (ay2 - ay1);
  float area_b = (bx2 - bx1) * (by2 - by1);
  float lx = fmaxf(ax1, bx1), ly = fmaxf(ay1, by1);
  float rx = fminf(ax2, bx2), ry = fminf(ay2, by2);
  float w = fmaxf(rx - lx, 0.0f), h = fmaxf(ry - ly, 0.0f);
  float inter = w * h;
  return inter / (area_a + area_b - inter + 1e-10f);
}

// ---------------- kernel 1: sort by score (desc) + precompute ----------------
__global__ __launch_bounds__(256) void k_sortprep(
    const int* __restrict__ agti_all,
    const float* __restrict__ gtb_all,
    const float* __restrict__ prop_all,
    unsigned char* __restrict__ ws) {
  const int b = blockIdx.x;
  const int tid = threadIdx.x;
  const int* agti = agti_all + b * NN;
  const float* gtb = gtb_all + b * GG * 4;
  const float* prop = prop_all + (size_t)b * NN * 5;
  unsigned char* W = ws + (size_t)b * IMG_STRIDE;
  float* gx1 = (float*)(W + OFF_X1);
  float* gy1 = (float*)(W + OFF_Y1);
  float* gx2 = (float*)(W + OFF_X2);
  float* gy2 = (float*)(W + OFF_Y2);
  float* gpull = (float*)(W + OFF_PULL);
  float* ggtpi = (float*)(W + OFF_GTPI);
  int* gagti = (int*)(W + OFF_AGTI);
  unsigned int* gcnt = (unsigned int*)(W + OFF_CNT);

  __shared__ unsigned long long keys[NN];
  __shared__ float sgt[GG * 4];

  if (tid < GG * 4) sgt[tid] = gtb[tid];
  for (int s = tid; s < NN; s += 256) {
    int a = agti[s];
    float sc = prop[s * 5 + 4];
    keys[s] = (a >= 0)
        ? ((unsigned long long)__float_as_uint(sc) << 32) | (unsigned)(~(unsigned)s)
        : 0ull;
    gcnt[s] = 0u;
  }
  __syncthreads();

  // bitonic sort, descending
  for (int k = 2; k <= NN; k <<= 1) {
    for (int j = k >> 1; j > 0; j >>= 1) {
      for (int i = tid; i < NN; i += 256) {
        int ixj = i ^ j;
        if (ixj > i) {
          unsigned long long a = keys[i], c = keys[ixj];
          bool up = ((i & k) == 0);
          if (up ? (a < c) : (a > c)) { keys[i] = c; keys[ixj] = a; }
        }
      }
      __syncthreads();
    }
  }

  if (tid == 0 && keys[0] == 0ull) *(unsigned int*)(W + OFF_NPOS) = 0u;
  for (int s = tid; s < NN; s += 256) {
    unsigned long long key = keys[s];
    if (key != 0ull && (s == NN - 1 || keys[s + 1] == 0ull))
      *(unsigned int*)(W + OFF_NPOS) = (unsigned)(s + 1);
    if (key != 0ull) {
      int orig = (int)(~(unsigned)(key & 0xffffffffull));
      float x1 = prop[orig * 5 + 0], y1 = prop[orig * 5 + 1];
      float x2 = prop[orig * 5 + 2], y2 = prop[orig * 5 + 3];
      float sc = __uint_as_float((unsigned)(key >> 32));
      int a = agti[orig];
      float gi = iou_pair(sgt[a * 4 + 0], sgt[a * 4 + 1], sgt[a * 4 + 2], sgt[a * 4 + 3],
                          x1, y1, x2, y2);
      gx1[s] = x1; gy1[s] = y1; gx2[s] = x2; gy2[s] = y2;
      gpull[s] = -logf(fminf(0.5f + fmaxf(gi, EPSF), 1.0f)) * sc;
      ggtpi[s] = gi;
      gagti[s] = a;
    } else {
      gx1[s] = 0.f; gy1[s] = 0.f; gx2[s] = 0.f; gy2[s] = 0.f;
      gpull[s] = 0.f; ggtpi[s] = 0.f; gagti[s] = -1;
    }
  }
}

// ---------------- kernel 2: sparse suppression lists (i<j, IoU>0.5) ---------
__global__ __launch_bounds__(256) void k_pairs(unsigned char* __restrict__ ws) {
  const int b = blockIdx.x >> 5;
  const int rblk = blockIdx.x & 31;
  unsigned char* W = ws + (size_t)b * IMG_STRIDE;
  const float* gx1 = (const float*)(W + OFF_X1);
  const float* gy1 = (const float*)(W + OFF_Y1);
  const float* gx2 = (const float*)(W + OFF_X2);
  const float* gy2 = (const float*)(W + OFF_Y2);
  unsigned int* gcnt = (unsigned int*)(W + OFF_CNT);
  unsigned short* gent = (unsigned short*)(W + OFF_ENT);
  const int npos = (int)*(const unsigned int*)(W + OFF_NPOS);
  const int wave = threadIdx.x >> 6, lane = threadIdx.x & 63;

  for (int rr = wave; rr < 64; rr += 4) {
    int i = rblk * 64 + rr;
    if (i >= npos) continue;
    float ax1 = gx1[i], ay1 = gy1[i], ax2 = gx2[i], ay2 = gy2[i];
    for (int j = i + 1 + lane; j < npos; j += 64) {
      float v = iou_pair(ax1, ay1, ax2, ay2, gx1[j], gy1[j], gx2[j], gy2[j]);
      if (v > NMS_T) {
        unsigned pos = atomicAdd(&gcnt[i], 1u);
        if (pos < CAP) gent[i * CAP + pos] = (unsigned short)j;
      }
    }
  }
}

// ---------------- kernel 3: serial scan (1 wave / image) ---------------------
__global__ __launch_bounds__(256) void k_scan(
    const float* __restrict__ gtb_all,
    unsigned char* __restrict__ ws) {
  const int b = blockIdx.x;
  const int tid = threadIdx.x;
  unsigned char* W = ws + (size_t)b * IMG_STRIDE;
  const float* gx1 = (const float*)(W + OFF_X1);
  const float* gy1 = (const float*)(W + OFF_Y1);
  const float* gx2 = (const float*)(W + OFF_X2);
  const float* gy2 = (const float*)(W + OFF_Y2);
  const float* gpull = (const float*)(W + OFF_PULL);
  const float* ggtpi = (const float*)(W + OFF_GTPI);
  const int* gagti = (const int*)(W + OFF_AGTI);
  const unsigned int* gcnt = (const unsigned int*)(W + OFF_CNT);
  const unsigned short* gent = (const unsigned short*)(W + OFF_ENT);
  const int npos = (int)*(const unsigned int*)(W + OFF_NPOS);
  const float* gtb = gtb_all + b * GG * 4;
  float* per_img = (float*)(ws + OFF_PERIMG);

  __shared__ unsigned short l_ent[NN * CAP];
  __shared__ float l_pull[NN];
  __shared__ signed char l_agti[NN];
  __shared__ unsigned char l_cnt[NN];
  __shared__ unsigned int bestg[GG];

  if (tid < GG) bestg[tid] = 0xffffffffu;
  __syncthreads();
  for (int s = tid; s < NN; s += 256) {
    l_pull[s] = gpull[s];
    int a = gagti[s];
    l_agti[s] = (signed char)a;
    unsigned c = gcnt[s];
    l_cnt[s] = (unsigned char)(c > CAP ? CAP + 1 : c);
    ((unsigned long long*)l_ent)[s * 3 + 0] = ((const unsigned long long*)gent)[s * 3 + 0];
    ((unsigned long long*)l_ent)[s * 3 + 1] = ((const unsigned long long*)gent)[s * 3 + 1];
    ((unsigned long long*)l_ent)[s * 3 + 2] = ((const unsigned long long*)gent)[s * 3 + 2];
    if (a >= 0 && s < npos) atomicMin(&bestg[a], (unsigned)s);
  }
  __syncthreads();

  if (tid < 64) {
    const int lane = tid;
    unsigned long long word = 0ull;
    if (lane < 32) {
      int rem = npos - (lane << 6);
      if (rem >= 64) word = ~0ull;
      else if (rem > 0) word = (1ull << rem) - 1ull;
    }
    unsigned long long prevw = 0ull, seen = 0ull;
    float tp = 0.f, pend = 0.f;
    int pc = 0;

    for (;;) {
      unsigned long long bal = __ballot(word != 0ull);
      if (bal == 0ull) break;
      prevw = word;
      int l0 = __ffsll((long long)bal) - 1;
      unsigned long long w0 = __shfl(word, l0, 64);
      int b0 = __ffsll((long long)w0) - 1;
      int i = (l0 << 6) + b0;

      int g = l_agti[i];
      float pull = l_pull[i];
      int c = l_cnt[i];
      bool sg = (seen >> g) & 1ull;
      tp += pend;
      pend = sg ? pull : 0.f;
      pc += sg ? 1 : 0;
      seen |= 1ull << (unsigned)g;

      if (lane == l0) word &= ~(1ull << b0);
      if (c > 0) {
        if (c <= CAP) {
          const unsigned long long* pe =
              (const unsigned long long*)(l_ent + i * CAP);
          unsigned long long p0 = pe[0], p1 = pe[1], p2 = pe[2];
          for (int e = 0; e < c; ++e) {
            unsigned long long pk = (e < 4) ? p0 : ((e < 8) ? p1 : p2);
            int j = (int)((pk >> ((e & 3) << 4)) & 0xffffull);
            if ((j >> 6) == lane) word &= ~(1ull << (j & 63));
          }
        } else {
          // overflow row: exact on-the-fly suppression (rare)
          float ax1 = gx1[i], ay1 = gy1[i], ax2 = gx2[i], ay2 = gy2[i];
          unsigned long long m = word;
          while (m) {
            int bb = __ffsll((long long)m) - 1;
            m &= m - 1ull;
            int j = (lane << 6) + bb;
            float v = iou_pair(ax1, ay1, ax2, ay2, gx1[j], gy1[j], gx2[j], gy2[j]);
            if (v > NMS_T) word &= ~(1ull << bb);
          }
        }
      }
    }

    // has_rem for the final selection: >=2 active at its selection time
    int kf = __popcll(prevw);
    #pragma unroll
    for (int off = 32; off; off >>= 1) kf += __shfl_xor(kf, off, 64);
    if (kf >= 2) tp += pend;

    // push term: lane == g
    float mypush = 0.f; int mycnt = 0;
    unsigned bj = bestg[lane];
    if (bj != 0xffffffffu) {
      float h = gtb[lane * 4 + 3] - gtb[lane * 4 + 1];
      if (h >= MIN_H && !((seen >> (unsigned)lane) & 1ull)) {
        mypush = 1.0f - ggtpi[bj];
        mycnt = 1;
      }
    }
    #pragma unroll
    for (int off = 32; off; off >>= 1) {
      mypush += __shfl_xor(mypush, off, 64);
      mycnt += __shfl_xor(mycnt, off, 64);
    }
    if (lane == 0) {
      float push_loss = 0.f, pull_loss = 0.f;
      if (npos > 1) {
        pull_loss = tp / ((float)pc + EPSF);
        push_loss = mypush / ((float)mycnt + EPSF);
      }
      per_img[b * 2 + 0] = push_loss;
      per_img[b * 2 + 1] = pull_loss;
    }
  }
}

__global__ void nms_loss_final(const unsigned char* __restrict__ ws,
                               float* __restrict__ out) {
  if (threadIdx.x == 0 && blockIdx.x == 0) {
    const float* per_img = (const float*)(ws + OFF_PERIMG);
    float sp = 0.f, sl = 0.f;
    for (int b = 0; b < B_IMG; ++b) {
      sp += per_img[b * 2 + 0];
      sl += per_img[b * 2 + 1];
    }
    out[0] = sp * (1.0f / B_IMG);
    out[1] = sl * (1.0f / B_IMG);
  }
}

extern "C" void kernel_launch(void* const* d_in, const int* in_sizes, int n_in,
                              void* d_out, int out_size, void* d_ws, size_t ws_size,
                              hipStream_t stream) {
  const int* agti = (const int*)d_in[1];
  const float* gtb = (const float*)d_in[2];
  const float* prop = (const float*)d_in[3];
  unsigned char* ws = (unsigned char*)d_ws;

  k_sortprep<<<B_IMG, 256, 0, stream>>>(agti, gtb, prop, ws);
  k_pairs<<<B_IMG * 32, 256, 0, stream>>>(ws);
  k_scan<<<B_IMG, 256, 0, stream>>>(gtb, ws);
  nms_loss_final<<<1, 64, 0, stream>>>(ws, (float*)d_out);
}

// Round 3
// 170.527 us; speedup vs baseline: 16.9371x; 3.0740x over previous
//
#include <hip/hip_runtime.h>
#include <math.h>

// NMSLoss4: B=8, N=2048, G=64. Sort-free formulation: sequential NMS ==
// unique fixed point of sel[j] = pos[j] && !(exists edge i->j, sel[i]) over
// the key-directed DAG (key = score desc, idx asc). Jacobi iteration to the
// fixed point, then order-free reductions for pull/push bookkeeping.

#define B_IMG 8
#define NN 2048
#define GG 64
#define NMS_T 0.5f
#define MIN_H 50.0f
#define EPSF 1e-6f
#define CAP 14

// per-image ws layout (bytes)
#define OFF_BOX   0              // float4[2048]   32768
#define OFF_KEY   32768          // u64[2048]      16384
#define OFF_GTPI  49152          // f32[2048]       8192
#define OFF_PULL  57344          // f32[2048]       8192
#define OFF_CNT   65536          // u32[2048]       8192
#define OFF_INL   73728          // u16[2048*CAP]  57344
#define OFF_AGTI  131072         // s8[2048]        2048
#define IMG_STRIDE 133120
#define OFF_PERIMG ((size_t)B_IMG * IMG_STRIDE)

__device__ __forceinline__ float iou_pair(
    float ax1, float ay1, float ax2, float ay2,
    float bx1, float by1, float bx2, float by2) {
  float area_a = (ax2 - ax1) * (ay2 - ay1);
  float area_b = (bx2 - bx1) * (by2 - by1);
  float lx = fmaxf(ax1, bx1), ly = fmaxf(ay1, by1);
  float rx = fminf(ax2, bx2), ry = fminf(ay2, by2);
  float w = fmaxf(rx - lx, 0.0f), h = fmaxf(ry - ly, 0.0f);
  float inter = w * h;
  return inter / (area_a + area_b - inter + 1e-10f);
}

// ---------------- kernel 1: per-box prep ------------------------------------
__global__ __launch_bounds__(256) void k_prep(
    const int* __restrict__ agti_all,
    const float* __restrict__ gtb_all,
    const float* __restrict__ prop_all,
    unsigned char* __restrict__ ws) {
  const int b = blockIdx.x, tid = threadIdx.x;
  const int* agti = agti_all + b * NN;
  const float* prop = prop_all + (size_t)b * NN * 5;
  unsigned char* W = ws + (size_t)b * IMG_STRIDE;
  float4* box = (float4*)(W + OFF_BOX);
  unsigned long long* keyA = (unsigned long long*)(W + OFF_KEY);
  float* gtpi = (float*)(W + OFF_GTPI);
  float* pull = (float*)(W + OFF_PULL);
  unsigned* cnt = (unsigned*)(W + OFF_CNT);
  signed char* ag8 = (signed char*)(W + OFF_AGTI);

  __shared__ float sgt[GG * 4];
  if (tid < GG * 4) sgt[tid] = gtb_all[b * GG * 4 + tid];
  __syncthreads();

  for (int e = tid; e < NN; e += 256) {
    float x1 = prop[e * 5 + 0], y1 = prop[e * 5 + 1];
    float x2 = prop[e * 5 + 2], y2 = prop[e * 5 + 3];
    float sc = prop[e * 5 + 4];
    int a = agti[e];
    unsigned long long key = 0ull;
    float gi = 0.f, pl = 0.f;
    if (a >= 0) {
      // higher key = earlier selection; ties -> lower idx (jnp.argmax).
      key = ((unsigned long long)__float_as_uint(sc) << 32) | (unsigned)(NN - 1 - e);
      gi = iou_pair(sgt[a * 4 + 0], sgt[a * 4 + 1], sgt[a * 4 + 2], sgt[a * 4 + 3],
                    x1, y1, x2, y2);
      pl = -logf(fminf(0.5f + fmaxf(gi, EPSF), 1.0f)) * sc;
    }
    box[e] = make_float4(x1, y1, x2, y2);
    keyA[e] = key;
    gtpi[e] = gi;
    pull[e] = pl;
    cnt[e] = 0u;
    ag8[e] = (signed char)a;
  }
}

// ---------------- kernel 2: in-edge lists (killer -> victim) ----------------
__global__ __launch_bounds__(256) void k_pairs(unsigned char* __restrict__ ws) {
  const int b = blockIdx.x >> 5, t = blockIdx.x & 31;
  unsigned char* W = ws + (size_t)b * IMG_STRIDE;
  const float4* box = (const float4*)(W + OFF_BOX);
  const unsigned long long* keyA = (const unsigned long long*)(W + OFF_KEY);
  unsigned* cnt = (unsigned*)(W + OFF_CNT);
  unsigned short* inl = (unsigned short*)(W + OFF_INL);
  const int wave = threadIdx.x >> 6, lane = threadIdx.x & 63;

  // triangle balancing: block handles rows {t*32..} and mirror {2047-...}.
  for (int rid = wave; rid < 64; rid += 4) {
    int a = (rid < 32) ? (t * 32 + rid) : (NN - 1 - (t * 32 + (rid - 32)));
    unsigned long long ka = keyA[a];
    if (!ka) continue;
    float4 A = box[a];
    for (int j = a + 1 + lane; j < NN; j += 64) {
      unsigned long long kb = keyA[j];
      if (!kb) continue;
      float4 Bx = box[j];
      float v;
      int hi, lo;
      if (ka > kb) {  // a selected-candidate first: iou(a_box, b_box)
        v = iou_pair(A.x, A.y, A.z, A.w, Bx.x, Bx.y, Bx.z, Bx.w);
        hi = a; lo = j;
      } else {
        v = iou_pair(Bx.x, Bx.y, Bx.z, Bx.w, A.x, A.y, A.z, A.w);
        hi = j; lo = a;
      }
      if (v > NMS_T) {
        unsigned p = atomicAdd(&cnt[lo], 1u);
        if (p < CAP) inl[lo * CAP + p] = (unsigned short)hi;
      }
    }
  }
}

// exact fallback for overflowed in-lists (expected never to run)
__device__ bool scan_kill(const unsigned char* W,
                          const unsigned long long* selw,
                          int e, unsigned long long mykey, int excl) {
  const float4* box = (const float4*)(W + OFF_BOX);
  const unsigned long long* keyA = (const unsigned long long*)(W + OFF_KEY);
  float4 E = box[e];
  for (int w = 0; w < 32; ++w) {
    unsigned long long m = selw[w];
    while (m) {
      int bit = __ffsll((long long)m) - 1;
      m &= m - 1ull;
      int i = w * 64 + bit;
      if (i == excl) continue;
      if (keyA[i] > mykey) {
        float4 I = box[i];
        if (iou_pair(I.x, I.y, I.z, I.w, E.x, E.y, E.z, E.w) > NMS_T) return true;
      }
    }
  }
  return false;
}

// ---------------- kernel 3: Jacobi fixed point + bookkeeping ----------------
__global__ __launch_bounds__(256) void k_resolve(
    const float* __restrict__ gtb_all,
    unsigned char* __restrict__ ws) {
  const int b = blockIdx.x, tid = threadIdx.x;
  const int wave = tid >> 6, lane = tid & 63;
  unsigned char* W = ws + (size_t)b * IMG_STRIDE;
  const unsigned long long* keyA = (const unsigned long long*)(W + OFF_KEY);
  const float* gtpi = (const float*)(W + OFF_GTPI);
  const float* pull = (const float*)(W + OFF_PULL);
  const unsigned* cnt = (const unsigned*)(W + OFF_CNT);
  const unsigned short* inl = (const unsigned short*)(W + OFF_INL);
  const signed char* ag8 = (const signed char*)(W + OFF_AGTI);
  float* per_img = (float*)(ws + OFF_PERIMG);

  __shared__ unsigned long long selw[32];
  __shared__ unsigned long long maxkeysel[GG], maxkeypos[GG];
  __shared__ unsigned selcnt[GG];
  __shared__ unsigned long long s_minkey;
  __shared__ int s_changed, s_hasrem, s_npos;
  __shared__ float wtp[4];

  unsigned long long mykey[8];
  unsigned mycnt[8];

  if (tid == 0) { s_changed = 0; s_hasrem = 0; s_npos = 0; s_minkey = ~0ull; }
  if (tid < GG) { maxkeysel[tid] = 0ull; maxkeypos[tid] = 0ull; selcnt[tid] = 0u; }
  __syncthreads();

  int nposp = 0;
  #pragma unroll
  for (int k = 0; k < 8; ++k) {
    int e = tid + k * 256;          // word index = k*4+wave, bit = lane
    mykey[k] = keyA[e];
    mycnt[k] = cnt[e];
    unsigned long long wb = __ballot(mykey[k] != 0ull);
    if (lane == 0) selw[k * 4 + wave] = wb;   // init: all positives selected
    nposp += (mykey[k] != 0ull) ? 1 : 0;
  }
  #pragma unroll
  for (int off = 32; off; off >>= 1) nposp += __shfl_xor(nposp, off, 64);
  if (lane == 0) atomicAdd(&s_npos, nposp);
  __syncthreads();

  // ---- Jacobi to the sequential-NMS fixed point (forward DAG => converges) ----
  for (;;) {
    #pragma unroll
    for (int k = 0; k < 8; ++k) {
      int e = tid + k * 256;
      bool sel;
      if (mykey[k] == 0ull) {
        sel = false;
      } else if (mycnt[k] == 0u) {
        sel = true;
      } else {
        bool killed = false;
        int c = mycnt[k] < CAP ? (int)mycnt[k] : CAP;
        for (int kk = 0; kk < c; ++kk) {
          int i = inl[e * CAP + kk];
          if ((selw[i >> 6] >> (i & 63)) & 1ull) { killed = true; break; }
        }
        if (!killed && mycnt[k] > CAP) killed = scan_kill(W, selw, e, mykey[k], -1);
        sel = !killed;
      }
      unsigned long long nw = __ballot(sel);
      if (lane == 0) {
        if (nw != selw[k * 4 + wave]) { selw[k * 4 + wave] = nw; s_changed = 1; }
      }
    }
    __syncthreads();
    if (!s_changed) break;
    __syncthreads();
    if (tid == 0) s_changed = 0;
    __syncthreads();
  }

  // ---- bookkeeping pass 1: per-g stats over selected / positive ----
  float tp_part = 0.f;
  #pragma unroll
  for (int k = 0; k < 8; ++k) {
    int e = tid + k * 256;
    if (mykey[k] != 0ull) {
      int g = ag8[e];
      atomicMax(&maxkeypos[g], mykey[k]);
      bool sel = (selw[k * 4 + wave] >> lane) & 1ull;
      if (sel) {
        atomicAdd(&selcnt[g], 1u);
        atomicMax(&maxkeysel[g], mykey[k]);
        atomicMin(&s_minkey, mykey[k]);
        tp_part += pull[e];
      }
    }
  }
  __syncthreads();

  // ---- pass 2: subtract first-of-g pulls; has_rem for the last selection ----
  const unsigned long long minkey = s_minkey;
  const int idx_last =
      (minkey != ~0ull) ? (NN - 1 - (int)(minkey & 0xffffffffull)) : -1;
  #pragma unroll
  for (int k = 0; k < 8; ++k) {
    int e = tid + k * 256;
    if (mykey[k] == 0ull) continue;
    bool sel = (selw[k * 4 + wave] >> lane) & 1ull;
    if (sel) {
      int g = ag8[e];
      if (mykey[k] == maxkeysel[g]) tp_part -= pull[e];  // first of its g
    } else {
      // killed box: active at i_last's turn iff its ONLY selected killer is i_last
      bool other = false;
      int c = mycnt[k] < CAP ? (int)mycnt[k] : CAP;
      for (int kk = 0; kk < c; ++kk) {
        int i = inl[e * CAP + kk];
        if (i != idx_last && ((selw[i >> 6] >> (i & 63)) & 1ull)) { other = true; break; }
      }
      if (!other && mycnt[k] > CAP) other = scan_kill(W, selw, e, mykey[k], idx_last);
      if (!other) s_hasrem = 1;
    }
  }
  #pragma unroll
  for (int off = 32; off; off >>= 1) tp_part += __shfl_xor(tp_part, off, 64);
  if (lane == 0) wtp[wave] = tp_part;
  __syncthreads();

  // ---- push term + finalize (wave 0; lane == g) ----
  if (wave == 0) {
    float mypush = 0.f;
    int mycnt2 = 0;
    unsigned long long kb = maxkeypos[lane];
    bool seen = selcnt[lane] > 0u;
    if (kb != 0ull) {
      float h = gtb_all[b * GG * 4 + lane * 4 + 3] - gtb_all[b * GG * 4 + lane * 4 + 1];
      if (h >= MIN_H && !seen) {
        int bj = NN - 1 - (int)(kb & 0xffffffffull);
        mypush = 1.0f - gtpi[bj];
        mycnt2 = 1;
      }
    }
    #pragma unroll
    for (int off = 32; off; off >>= 1) {
      mypush += __shfl_xor(mypush, off, 64);
      mycnt2 += __shfl_xor(mycnt2, off, 64);
    }
    if (lane == 0) {
      float tp = wtp[0] + wtp[1] + wtp[2] + wtp[3];
      int total_sel = 0;
      for (int w = 0; w < 32; ++w) total_sel += __popcll(selw[w]);
      int distinct = 0;
      for (int g = 0; g < GG; ++g) distinct += (selcnt[g] > 0u) ? 1 : 0;
      int pc = total_sel - distinct;
      if (idx_last >= 0) {
        int gl = ag8[idx_last];
        // last selection: its pull only counts if non-first-of-g AND has_rem
        if (minkey != maxkeysel[gl] && !s_hasrem) tp -= pull[idx_last];
      }
      float push_loss = 0.f, pull_loss = 0.f;
      if (s_npos > 1) {
        pull_loss = tp / ((float)pc + EPSF);
        push_loss = mypush / ((float)mycnt2 + EPSF);
      }
      per_img[b * 2 + 0] = push_loss;
      per_img[b * 2 + 1] = pull_loss;
    }
  }
}

__global__ void nms_loss_final(const unsigned char* __restrict__ ws,
                               float* __restrict__ out) {
  if (threadIdx.x == 0 && blockIdx.x == 0) {
    const float* per_img = (const float*)(ws + OFF_PERIMG);
    float sp = 0.f, sl = 0.f;
    for (int b = 0; b < B_IMG; ++b) {
      sp += per_img[b * 2 + 0];
      sl += per_img[b * 2 + 1];
    }
    out[0] = sp * (1.0f / B_IMG);
    out[1] = sl * (1.0f / B_IMG);
  }
}

extern "C" void kernel_launch(void* const* d_in, const int* in_sizes, int n_in,
                              void* d_out, int out_size, void* d_ws, size_t ws_size,
                              hipStream_t stream) {
  const int* agti = (const int*)d_in[1];
  const float* gtb = (const float*)d_in[2];
  const float* prop = (const float*)d_in[3];
  unsigned char* ws = (unsigned char*)d_ws;

  k_prep<<<B_IMG, 256, 0, stream>>>(agti, gtb, prop, ws);
  k_pairs<<<B_IMG * 32, 256, 0, stream>>>(ws);
  k_resolve<<<B_IMG, 256, 0, stream>>>(gtb, ws);
  nms_loss_final<<<1, 64, 0, stream>>>(ws, (float*)d_out);
}

// Round 4
// 112.684 us; speedup vs baseline: 25.6314x; 1.5133x over previous
//
#include <hip/hip_runtime.h>
#include <math.h>

// NMSLoss4: B=8, N=2048, G=64. Sequential NMS == unique fixed point of
// sel[j] = pos[j] && !(exists edge i->j with sel[i]) over the key-directed
// forward DAG (key = score desc, idx asc). Jacobi to the fixed point, then
// order-free reductions. Round 3: tiled LDS all-pairs, LDS-staged in-edge
// lists in resolve, final reduction fused via atomicAdd.

#define B_IMG 8
#define NN 2048
#define GG 64
#define NMS_T 0.5f
#define MIN_H 50.0f
#define EPSF 1e-6f
#define CAP 14
#define TILE 256
#define NTILE (NN / TILE)                 // 8
#define NPAIRT (NTILE * (NTILE + 1) / 2)  // 36

// per-image ws layout (bytes)
#define OFF_BOX   0              // float4[2048]   32768
#define OFF_KEY   32768          // u64[2048]      16384
#define OFF_GTPI  49152          // f32[2048]       8192
#define OFF_PULL  57344          // f32[2048]       8192
#define OFF_CNT   65536          // u32[2048]       8192
#define OFF_INL   73728          // u16[2048*CAP]  57344
#define OFF_AGTI  131072         // s8[2048]        2048
#define IMG_STRIDE 133120

__device__ __forceinline__ float iou_pair(
    float ax1, float ay1, float ax2, float ay2,
    float bx1, float by1, float bx2, float by2) {
  float area_a = (ax2 - ax1) * (ay2 - ay1);
  float area_b = (bx2 - bx1) * (by2 - by1);
  float lx = fmaxf(ax1, bx1), ly = fmaxf(ay1, by1);
  float rx = fminf(ax2, bx2), ry = fminf(ay2, by2);
  float w = fmaxf(rx - lx, 0.0f), h = fmaxf(ry - ly, 0.0f);
  float inter = w * h;
  return inter / (area_a + area_b - inter + 1e-10f);
}

// ---------------- kernel 1: per-box prep (64 blocks) + zero d_out -----------
__global__ __launch_bounds__(256) void k_prep(
    const int* __restrict__ agti_all,
    const float* __restrict__ gtb_all,
    const float* __restrict__ prop_all,
    unsigned char* __restrict__ ws,
    float* __restrict__ out) {
  const int b = blockIdx.x >> 3, chunk = blockIdx.x & 7;
  const int tid = threadIdx.x;
  const int e = chunk * TILE + tid;
  const int* agti = agti_all + b * NN;
  const float* prop = prop_all + (size_t)b * NN * 5;
  unsigned char* W = ws + (size_t)b * IMG_STRIDE;

  if (blockIdx.x == 0 && tid == 0) { out[0] = 0.f; out[1] = 0.f; }

  __shared__ float sgt[GG * 4];
  sgt[tid] = gtb_all[b * GG * 4 + tid];
  __syncthreads();

  float x1 = prop[e * 5 + 0], y1 = prop[e * 5 + 1];
  float x2 = prop[e * 5 + 2], y2 = prop[e * 5 + 3];
  float sc = prop[e * 5 + 4];
  int a = agti[e];
  unsigned long long key = 0ull;
  float gi = 0.f, pl = 0.f;
  if (a >= 0) {
    // higher key = earlier selection; ties -> lower idx (jnp.argmax).
    key = ((unsigned long long)__float_as_uint(sc) << 32) | (unsigned)(NN - 1 - e);
    gi = iou_pair(sgt[a * 4 + 0], sgt[a * 4 + 1], sgt[a * 4 + 2], sgt[a * 4 + 3],
                  x1, y1, x2, y2);
    pl = -logf(fminf(0.5f + fmaxf(gi, EPSF), 1.0f)) * sc;
  }
  ((float4*)(W + OFF_BOX))[e] = make_float4(x1, y1, x2, y2);
  ((unsigned long long*)(W + OFF_KEY))[e] = key;
  ((float*)(W + OFF_GTPI))[e] = gi;
  ((float*)(W + OFF_PULL))[e] = pl;
  ((unsigned*)(W + OFF_CNT))[e] = 0u;
  ((signed char*)(W + OFF_AGTI))[e] = (signed char)a;
}

// ---------------- kernel 2: tiled all-pairs -> in-edge lists ----------------
__global__ __launch_bounds__(256) void k_pairs(unsigned char* __restrict__ ws) {
  const int b = blockIdx.x / NPAIRT;
  int p = blockIdx.x % NPAIRT;
  int r = 0;
  #pragma unroll
  for (int q = 0; q < NTILE; ++q) {
    int width = NTILE - q;
    if (p < width) { r = q; break; }
    p -= width;
  }
  const int c = r + p;
  const int tid = threadIdx.x;
  unsigned char* W = ws + (size_t)b * IMG_STRIDE;
  const float4* box = (const float4*)(W + OFF_BOX);
  const unsigned long long* keyA = (const unsigned long long*)(W + OFF_KEY);
  unsigned* cnt = (unsigned*)(W + OFF_CNT);
  unsigned short* inl = (unsigned short*)(W + OFF_INL);

  __shared__ float4 cbox[TILE];
  __shared__ unsigned long long ckey[TILE];

  const int i = r * TILE + tid;
  const float4 A = box[i];
  const unsigned long long ka = keyA[i];
  {
    const int j = c * TILE + tid;
    cbox[tid] = box[j];
    ckey[tid] = keyA[j];
  }
  __syncthreads();

  if (ka != 0ull) {
    const int start = (r == c) ? tid + 1 : 0;
    for (int jj = start; jj < TILE; ++jj) {
      unsigned long long kb = ckey[jj];     // block-uniform LDS broadcast
      if (kb == 0ull) continue;
      float4 Bx = cbox[jj];
      float v = iou_pair(A.x, A.y, A.z, A.w, Bx.x, Bx.y, Bx.z, Bx.w);
      if (v > NMS_T) {
        int j = c * TILE + jj;
        int hi = (ka > kb) ? i : j;
        int lo = (ka > kb) ? j : i;
        unsigned pos = atomicAdd(&cnt[lo], 1u);
        if (pos < CAP) inl[lo * CAP + pos] = (unsigned short)hi;
      }
    }
  }
}

// exact fallback for overflowed in-lists (expected never to run)
__device__ bool scan_kill(const unsigned char* W,
                          const unsigned long long* selw,
                          int e, unsigned long long mykey, int excl) {
  const float4* box = (const float4*)(W + OFF_BOX);
  const unsigned long long* keyA = (const unsigned long long*)(W + OFF_KEY);
  float4 E = box[e];
  for (int w = 0; w < 32; ++w) {
    unsigned long long m = selw[w];
    while (m) {
      int bit = __ffsll((long long)m) - 1;
      m &= m - 1ull;
      int i = w * 64 + bit;
      if (i == excl) continue;
      if (keyA[i] > mykey) {
        float4 I = box[i];
        if (iou_pair(I.x, I.y, I.z, I.w, E.x, E.y, E.z, E.w) > NMS_T) return true;
      }
    }
  }
  return false;
}

// ---------------- kernel 3: Jacobi fixed point + bookkeeping + final --------
__global__ __launch_bounds__(256) void k_resolve(
    const float* __restrict__ gtb_all,
    unsigned char* __restrict__ ws,
    float* __restrict__ out) {
  const int b = blockIdx.x, tid = threadIdx.x;
  const int wave = tid >> 6, lane = tid & 63;
  unsigned char* W = ws + (size_t)b * IMG_STRIDE;
  const unsigned long long* keyA = (const unsigned long long*)(W + OFF_KEY);
  const float* gtpi = (const float*)(W + OFF_GTPI);
  const float* pull = (const float*)(W + OFF_PULL);
  const unsigned* cnt = (const unsigned*)(W + OFF_CNT);
  const signed char* ag8 = (const signed char*)(W + OFF_AGTI);

  __shared__ __align__(16) unsigned short inl_l[NN * CAP];  // 57344 B
  __shared__ unsigned long long selw[32];
  __shared__ unsigned long long maxkeysel[GG], maxkeypos[GG];
  __shared__ unsigned selcnt[GG];
  __shared__ unsigned long long s_minkey;
  __shared__ int s_changed, s_hasrem, s_npos;
  __shared__ float wtp[4];

  unsigned long long mykey[8];
  unsigned mycnt[8];

  if (tid == 0) { s_changed = 0; s_hasrem = 0; s_npos = 0; s_minkey = ~0ull; }
  if (tid < GG) { maxkeysel[tid] = 0ull; maxkeypos[tid] = 0ull; selcnt[tid] = 0u; }

  // stage the in-edge table into LDS (3584 uint4)
  {
    const uint4* src = (const uint4*)(W + OFF_INL);
    uint4* dst = (uint4*)inl_l;
    #pragma unroll
    for (int k = 0; k < 14; ++k) dst[tid + k * 256] = src[tid + k * 256];
  }

  int nposp = 0;
  #pragma unroll
  for (int k = 0; k < 8; ++k) {
    int e = tid + k * 256;          // word index = k*4+wave, bit = lane
    mykey[k] = keyA[e];
    mycnt[k] = cnt[e];
    unsigned long long wb = __ballot(mykey[k] != 0ull);
    if (lane == 0) selw[k * 4 + wave] = wb;   // init: all positives selected
    nposp += (mykey[k] != 0ull) ? 1 : 0;
  }
  #pragma unroll
  for (int off = 32; off; off >>= 1) nposp += __shfl_xor(nposp, off, 64);
  if (lane == 0) atomicAdd(&s_npos, nposp);
  __syncthreads();

  // ---- Jacobi to the sequential-NMS fixed point (forward DAG => converges) --
  for (;;) {
    #pragma unroll
    for (int k = 0; k < 8; ++k) {
      int e = tid + k * 256;
      bool sel;
      if (mykey[k] == 0ull) {
        sel = false;
      } else if (mycnt[k] == 0u) {
        sel = true;
      } else {
        bool killed = false;
        int c = mycnt[k] < CAP ? (int)mycnt[k] : CAP;
        for (int kk = 0; kk < c; ++kk) {
          int i = inl_l[e * CAP + kk];
          if ((selw[i >> 6] >> (i & 63)) & 1ull) { killed = true; break; }
        }
        if (!killed && mycnt[k] > CAP) killed = scan_kill(W, selw, e, mykey[k], -1);
        sel = !killed;
      }
      unsigned long long nw = __ballot(sel);
      if (lane == 0) {
        if (nw != selw[k * 4 + wave]) { selw[k * 4 + wave] = nw; s_changed = 1; }
      }
    }
    __syncthreads();
    if (!s_changed) break;
    __syncthreads();
    if (tid == 0) s_changed = 0;
    __syncthreads();
  }

  // ---- bookkeeping pass 1: per-g stats over selected / positive ----
  float tp_part = 0.f;
  #pragma unroll
  for (int k = 0; k < 8; ++k) {
    int e = tid + k * 256;
    if (mykey[k] != 0ull) {
      int g = ag8[e];
      atomicMax(&maxkeypos[g], mykey[k]);
      bool sel = (selw[k * 4 + wave] >> lane) & 1ull;
      if (sel) {
        atomicAdd(&selcnt[g], 1u);
        atomicMax(&maxkeysel[g], mykey[k]);
        atomicMin(&s_minkey, mykey[k]);
        tp_part += pull[e];
      }
    }
  }
  __syncthreads();

  // ---- pass 2: subtract first-of-g pulls; has_rem for the last selection ----
  const unsigned long long minkey = s_minkey;
  const int idx_last =
      (minkey != ~0ull) ? (NN - 1 - (int)(minkey & 0xffffffffull)) : -1;
  #pragma unroll
  for (int k = 0; k < 8; ++k) {
    int e = tid + k * 256;
    if (mykey[k] == 0ull) continue;
    bool sel = (selw[k * 4 + wave] >> lane) & 1ull;
    if (sel) {
      int g = ag8[e];
      if (mykey[k] == maxkeysel[g]) tp_part -= pull[e];  // first of its g
    } else {
      // killed box: active at i_last's turn iff its ONLY selected killer is i_last
      bool other = false;
      int c = mycnt[k] < CAP ? (int)mycnt[k] : CAP;
      for (int kk = 0; kk < c; ++kk) {
        int i = inl_l[e * CAP + kk];
        if (i != idx_last && ((selw[i >> 6] >> (i & 63)) & 1ull)) { other = true; break; }
      }
      if (!other && mycnt[k] > CAP) other = scan_kill(W, selw, e, mykey[k], idx_last);
      if (!other) s_hasrem = 1;
    }
  }
  #pragma unroll
  for (int off = 32; off; off >>= 1) tp_part += __shfl_xor(tp_part, off, 64);
  if (lane == 0) wtp[wave] = tp_part;
  __syncthreads();

  // ---- push term + finalize (wave 0; lane == g), fused final reduction ----
  if (wave == 0) {
    float mypush = 0.f;
    int mycnt2 = 0;
    unsigned long long kb = maxkeypos[lane];
    bool seen = selcnt[lane] > 0u;
    if (kb != 0ull) {
      float h = gtb_all[b * GG * 4 + lane * 4 + 3] - gtb_all[b * GG * 4 + lane * 4 + 1];
      if (h >= MIN_H && !seen) {
        int bj = NN - 1 - (int)(kb & 0xffffffffull);
        mypush = 1.0f - gtpi[bj];
        mycnt2 = 1;
      }
    }
    #pragma unroll
    for (int off = 32; off; off >>= 1) {
      mypush += __shfl_xor(mypush, off, 64);
      mycnt2 += __shfl_xor(mycnt2, off, 64);
    }
    if (lane == 0) {
      float tp = wtp[0] + wtp[1] + wtp[2] + wtp[3];
      int total_sel = 0;
      for (int w = 0; w < 32; ++w) total_sel += __popcll(selw[w]);
      int distinct = 0;
      for (int g = 0; g < GG; ++g) distinct += (selcnt[g] > 0u) ? 1 : 0;
      int pc = total_sel - distinct;
      if (idx_last >= 0) {
        int gl = ag8[idx_last];
        // last selection: its pull only counts if non-first-of-g AND has_rem
        if (minkey != maxkeysel[gl] && !s_hasrem) tp -= pull[idx_last];
      }
      float push_loss = 0.f, pull_loss = 0.f;
      if (s_npos > 1) {
        pull_loss = tp / ((float)pc + EPSF);
        push_loss = mypush / ((float)mycnt2 + EPSF);
      }
      atomicAdd(&out[0], push_loss * (1.0f / B_IMG));
      atomicAdd(&out[1], pull_loss * (1.0f / B_IMG));
    }
  }
}

extern "C" void kernel_launch(void* const* d_in, const int* in_sizes, int n_in,
                              void* d_out, int out_size, void* d_ws, size_t ws_size,
                              hipStream_t stream) {
  const int* agti = (const int*)d_in[1];
  const float* gtb = (const float*)d_in[2];
  const float* prop = (const float*)d_in[3];
  unsigned char* ws = (unsigned char*)d_ws;
  float* out = (float*)d_out;

  k_prep<<<B_IMG * 8, 256, 0, stream>>>(agti, gtb, prop, ws, out);
  k_pairs<<<B_IMG * NPAIRT, 256, 0, stream>>>(ws);
  k_resolve<<<B_IMG, 256, 0, stream>>>(gtb, ws, out);
}

// Round 5
// 64.791 us; speedup vs baseline: 44.5781x; 1.7392x over previous
//
#include <hip/hip_runtime.h>
#include <math.h>

// NMSLoss4: B=8, N=2048, G=64. Sequential NMS == unique fixed point of
// sel[j] = pos[j] && !(exists edge i->j with sel[i]) over the key-directed
// forward DAG (key = score desc, idx asc). Jacobi to the fixed point, then
// order-free reductions. Round 4: branch-free divide-free pairs kernel with
// 4x grid; resolve reads edge lists from L2 with CAP=24, 512 threads.

#define B_IMG 8
#define NN 2048
#define GG 64
#define NMS_T 0.5f
#define MIN_H 50.0f
#define EPSF 1e-6f
#define CAP 24
#define TILE 256
#define NTILE (NN / TILE)                 // 8
#define NPAIRT (NTILE * (NTILE + 1) / 2)  // 36
#define CSLICE 64

// per-image ws layout (bytes)
#define OFF_BOX   0              // float4[2048]   32768
#define OFF_KEY   32768          // u64[2048]      16384
#define OFF_GTPI  49152          // f32[2048]       8192
#define OFF_PULL  57344          // f32[2048]       8192
#define OFF_CNT   65536          // u32[2048]       8192
#define OFF_AGTI  73728          // s8[2048]        2048
#define OFF_INL   75776          // u16[2048*CAP]  98304
#define IMG_STRIDE 174080

__device__ __forceinline__ float iou_pair(
    float ax1, float ay1, float ax2, float ay2,
    float bx1, float by1, float bx2, float by2) {
  float area_a = (ax2 - ax1) * (ay2 - ay1);
  float area_b = (bx2 - bx1) * (by2 - by1);
  float lx = fmaxf(ax1, bx1), ly = fmaxf(ay1, by1);
  float rx = fminf(ax2, bx2), ry = fminf(ay2, by2);
  float w = fmaxf(rx - lx, 0.0f), h = fmaxf(ry - ly, 0.0f);
  float inter = w * h;
  return inter / (area_a + area_b - inter + 1e-10f);
}

// ---------------- kernel 1: per-box prep (64 blocks) + zero d_out -----------
__global__ __launch_bounds__(256) void k_prep(
    const int* __restrict__ agti_all,
    const float* __restrict__ gtb_all,
    const float* __restrict__ prop_all,
    unsigned char* __restrict__ ws,
    float* __restrict__ out) {
  const int b = blockIdx.x >> 3, chunk = blockIdx.x & 7;
  const int tid = threadIdx.x;
  const int e = chunk * TILE + tid;
  const int* agti = agti_all + b * NN;
  const float* prop = prop_all + (size_t)b * NN * 5;
  unsigned char* W = ws + (size_t)b * IMG_STRIDE;

  if (blockIdx.x == 0 && tid == 0) { out[0] = 0.f; out[1] = 0.f; }

  __shared__ float sgt[GG * 4];
  sgt[tid] = gtb_all[b * GG * 4 + tid];
  __syncthreads();

  float x1 = prop[e * 5 + 0], y1 = prop[e * 5 + 1];
  float x2 = prop[e * 5 + 2], y2 = prop[e * 5 + 3];
  float sc = prop[e * 5 + 4];
  int a = agti[e];
  unsigned long long key = 0ull;
  float gi = 0.f, pl = 0.f;
  if (a >= 0) {
    // higher key = earlier selection; ties -> lower idx (jnp.argmax).
    key = ((unsigned long long)__float_as_uint(sc) << 32) | (unsigned)(NN - 1 - e);
    gi = iou_pair(sgt[a * 4 + 0], sgt[a * 4 + 1], sgt[a * 4 + 2], sgt[a * 4 + 3],
                  x1, y1, x2, y2);
    pl = -logf(fminf(0.5f + fmaxf(gi, EPSF), 1.0f)) * sc;
  }
  ((float4*)(W + OFF_BOX))[e] = make_float4(x1, y1, x2, y2);
  ((unsigned long long*)(W + OFF_KEY))[e] = key;
  ((float*)(W + OFF_GTPI))[e] = gi;
  ((float*)(W + OFF_PULL))[e] = pl;
  ((unsigned*)(W + OFF_CNT))[e] = 0u;
  ((signed char*)(W + OFF_AGTI))[e] = (signed char)a;
}

// ---------------- kernel 2: tiled all-pairs -> in-edge lists ----------------
// Branch-free inner loop; exact divide-free IoU>0.5 predicate:
// fl32(inter/denom) > 0.5f  <=>  inter/denom > 0.5+2^-25 (RNE, tie->0.5 even)
// <=>  (double)inter > (0.5+2^-25)*(double)denom   (product exact: 24+25 bits)
__global__ __launch_bounds__(256) void k_pairs(unsigned char* __restrict__ ws) {
  int bx = blockIdx.x;
  const int b = bx / (NPAIRT * 4);
  int rem = bx % (NPAIRT * 4);
  int p = rem >> 2;
  const int q = rem & 3;
  int r = 0;
  #pragma unroll
  for (int t = 0; t < NTILE; ++t) {
    int wdt = NTILE - t;
    if (p < wdt) { r = t; break; }
    p -= wdt;
  }
  const int c = r + p;
  const int tid = threadIdx.x;
  unsigned char* W = ws + (size_t)b * IMG_STRIDE;
  const float4* box = (const float4*)(W + OFF_BOX);
  const unsigned long long* keyA = (const unsigned long long*)(W + OFF_KEY);
  unsigned* cnt = (unsigned*)(W + OFF_CNT);
  unsigned short* inl = (unsigned short*)(W + OFF_INL);

  __shared__ float4 cbox[CSLICE];
  __shared__ float4 caux[CSLICE];   // (area_b, key_hi, key_lo, -)

  const int jbase = c * TILE + q * CSLICE;
  if (tid < CSLICE) {
    int j = jbase + tid;
    float4 Bx = box[j];
    unsigned long long kb = keyA[j];
    cbox[tid] = Bx;
    caux[tid] = make_float4((Bx.z - Bx.x) * (Bx.w - Bx.y),
                            __uint_as_float((unsigned)(kb >> 32)),
                            __uint_as_float((unsigned)kb), 0.f);
  }
  const int i = r * TILE + tid;
  const float4 A = box[i];
  const unsigned long long ka = keyA[i];
  const float area_a = (A.z - A.x) * (A.w - A.y);
  __syncthreads();

  const double THR = 0.5 + 0x1p-25;
  #pragma unroll 8
  for (int jj = 0; jj < CSLICE; ++jj) {
    float4 Bx = cbox[jj];
    float4 ax = caux[jj];
    float lx = fmaxf(A.x, Bx.x), ly = fmaxf(A.y, Bx.y);
    float rx = fminf(A.z, Bx.z), ry = fminf(A.w, Bx.w);
    float w = fmaxf(rx - lx, 0.0f), h = fmaxf(ry - ly, 0.0f);
    float inter = w * h;
    float denom = area_a + ax.x - inter + 1e-10f;  // ((aa+ab)-inter)+eps
    unsigned long long kb =
        ((unsigned long long)__float_as_uint(ax.y) << 32) | __float_as_uint(ax.z);
    int j = jbase + jj;
    bool hit = ((double)inter > THR * (double)denom) &&
               (ka != 0ull) && (kb != 0ull) && (j > i);
    if (hit) {
      int hi = (ka > kb) ? i : j;
      int lo = (ka > kb) ? j : i;
      unsigned pos = atomicAdd(&cnt[lo], 1u);
      if (pos < CAP) inl[lo * CAP + pos] = (unsigned short)hi;
    }
  }
}

// exact fallback for overflowed in-lists (rare)
__device__ bool scan_kill(const unsigned char* W,
                          const unsigned long long* selw,
                          int e, unsigned long long mykey, int excl) {
  const float4* box = (const float4*)(W + OFF_BOX);
  const unsigned long long* keyA = (const unsigned long long*)(W + OFF_KEY);
  float4 E = box[e];
  for (int w = 0; w < 32; ++w) {
    unsigned long long m = selw[w];
    while (m) {
      int bit = __ffsll((long long)m) - 1;
      m &= m - 1ull;
      int i = w * 64 + bit;
      if (i == excl) continue;
      if (keyA[i] > mykey) {
        float4 I = box[i];
        if (iou_pair(I.x, I.y, I.z, I.w, E.x, E.y, E.z, E.w) > NMS_T) return true;
      }
    }
  }
  return false;
}

// ---------------- kernel 3: Jacobi fixed point + bookkeeping + final --------
#define RTHREADS 512
#define SLOTS 4
__global__ __launch_bounds__(RTHREADS) void k_resolve(
    const float* __restrict__ gtb_all,
    unsigned char* __restrict__ ws,
    float* __restrict__ out) {
  const int b = blockIdx.x, tid = threadIdx.x;
  const int wave = tid >> 6, lane = tid & 63;
  unsigned char* W = ws + (size_t)b * IMG_STRIDE;
  const unsigned long long* keyA = (const unsigned long long*)(W + OFF_KEY);
  const float* gtpi = (const float*)(W + OFF_GTPI);
  const float* pull = (const float*)(W + OFF_PULL);
  const unsigned* cnt = (const unsigned*)(W + OFF_CNT);
  const signed char* ag8 = (const signed char*)(W + OFF_AGTI);
  const unsigned short* inl = (const unsigned short*)(W + OFF_INL);

  __shared__ unsigned long long selw[32];
  __shared__ unsigned long long maxkeysel[GG], maxkeypos[GG];
  __shared__ unsigned selcnt[GG];
  __shared__ unsigned long long s_minkey;
  __shared__ int s_changed, s_hasrem, s_npos;
  __shared__ float wtp[8];

  unsigned long long mykey[SLOTS];
  unsigned mycnt[SLOTS];

  if (tid == 0) { s_changed = 0; s_hasrem = 0; s_npos = 0; s_minkey = ~0ull; }
  if (tid < GG) { maxkeysel[tid] = 0ull; maxkeypos[tid] = 0ull; selcnt[tid] = 0u; }

  int nposp = 0;
  #pragma unroll
  for (int k = 0; k < SLOTS; ++k) {
    int e = tid + k * RTHREADS;     // word index = k*8+wave, bit = lane
    mykey[k] = keyA[e];
    mycnt[k] = cnt[e];
    unsigned long long wb = __ballot(mykey[k] != 0ull);
    if (lane == 0) selw[k * 8 + wave] = wb;   // init: all positives selected
    nposp += (mykey[k] != 0ull) ? 1 : 0;
  }
  #pragma unroll
  for (int off = 32; off; off >>= 1) nposp += __shfl_xor(nposp, off, 64);
  if (lane == 0) atomicAdd(&s_npos, nposp);
  __syncthreads();

  // ---- Jacobi to the sequential-NMS fixed point ----
  for (;;) {
    #pragma unroll
    for (int k = 0; k < SLOTS; ++k) {
      int e = tid + k * RTHREADS;
      bool sel;
      if (mykey[k] == 0ull) {
        sel = false;
      } else {
        unsigned long long kill = 0ull;
        int ce = mycnt[k] < CAP ? (int)mycnt[k] : CAP;
        for (int kk = 0; kk < ce; ++kk) {
          int idx = inl[e * CAP + kk];
          kill |= (selw[idx >> 6] >> (idx & 63)) & 1ull;   // independent reads
        }
        bool killed = (kill != 0ull);
        if (!killed && mycnt[k] > CAP) killed = scan_kill(W, selw, e, mykey[k], -1);
        sel = !killed;
      }
      unsigned long long nw = __ballot(sel);
      if (lane == 0 && nw != selw[k * 8 + wave]) { selw[k * 8 + wave] = nw; s_changed = 1; }
    }
    __syncthreads();
    if (!s_changed) break;
    __syncthreads();
    if (tid == 0) s_changed = 0;
    __syncthreads();
  }

  // ---- bookkeeping pass 1: per-g stats over selected / positive ----
  float tp_part = 0.f;
  #pragma unroll
  for (int k = 0; k < SLOTS; ++k) {
    int e = tid + k * RTHREADS;
    if (mykey[k] != 0ull) {
      int g = ag8[e];
      atomicMax(&maxkeypos[g], mykey[k]);
      bool sel = (selw[k * 8 + wave] >> lane) & 1ull;
      if (sel) {
        atomicAdd(&selcnt[g], 1u);
        atomicMax(&maxkeysel[g], mykey[k]);
        atomicMin(&s_minkey, mykey[k]);
        tp_part += pull[e];
      }
    }
  }
  __syncthreads();

  // ---- pass 2: subtract first-of-g pulls; has_rem for the last selection ----
  const unsigned long long minkey = s_minkey;
  const int idx_last =
      (minkey != ~0ull) ? (NN - 1 - (int)(minkey & 0xffffffffull)) : -1;
  #pragma unroll
  for (int k = 0; k < SLOTS; ++k) {
    int e = tid + k * RTHREADS;
    if (mykey[k] == 0ull) continue;
    bool sel = (selw[k * 8 + wave] >> lane) & 1ull;
    if (sel) {
      int g = ag8[e];
      if (mykey[k] == maxkeysel[g]) tp_part -= pull[e];  // first of its g
    } else {
      // killed box: active at i_last's turn iff its ONLY selected killer is i_last
      bool other = false;
      int ce = mycnt[k] < CAP ? (int)mycnt[k] : CAP;
      for (int kk = 0; kk < ce; ++kk) {
        int idx = inl[e * CAP + kk];
        if (idx != idx_last && ((selw[idx >> 6] >> (idx & 63)) & 1ull)) { other = true; break; }
      }
      if (!other && mycnt[k] > CAP) other = scan_kill(W, selw, e, mykey[k], idx_last);
      if (!other) s_hasrem = 1;
    }
  }
  #pragma unroll
  for (int off = 32; off; off >>= 1) tp_part += __shfl_xor(tp_part, off, 64);
  if (lane == 0) wtp[wave] = tp_part;
  __syncthreads();

  // ---- push term + finalize (wave 0; lane == g), fused final reduction ----
  if (wave == 0) {
    float mypush = 0.f;
    int mycnt2 = 0;
    unsigned long long kb = maxkeypos[lane];
    bool seen = selcnt[lane] > 0u;
    if (kb != 0ull) {
      float h = gtb_all[b * GG * 4 + lane * 4 + 3] - gtb_all[b * GG * 4 + lane * 4 + 1];
      if (h >= MIN_H && !seen) {
        int bj = NN - 1 - (int)(kb & 0xffffffffull);
        mypush = 1.0f - gtpi[bj];
        mycnt2 = 1;
      }
    }
    #pragma unroll
    for (int off = 32; off; off >>= 1) {
      mypush += __shfl_xor(mypush, off, 64);
      mycnt2 += __shfl_xor(mycnt2, off, 64);
    }
    if (lane == 0) {
      float tp = 0.f;
      for (int w = 0; w < 8; ++w) tp += wtp[w];
      int total_sel = 0;
      for (int w = 0; w < 32; ++w) total_sel += __popcll(selw[w]);
      int distinct = 0;
      for (int g = 0; g < GG; ++g) distinct += (selcnt[g] > 0u) ? 1 : 0;
      int pc = total_sel - distinct;
      if (idx_last >= 0) {
        int gl = ag8[idx_last];
        // last selection: its pull only counts if non-first-of-g AND has_rem
        if (minkey != maxkeysel[gl] && !s_hasrem) tp -= pull[idx_last];
      }
      float push_loss = 0.f, pull_loss = 0.f;
      if (s_npos > 1) {
        pull_loss = tp / ((float)pc + EPSF);
        push_loss = mypush / ((float)mycnt2 + EPSF);
      }
      atomicAdd(&out[0], push_loss * (1.0f / B_IMG));
      atomicAdd(&out[1], pull_loss * (1.0f / B_IMG));
    }
  }
}

extern "C" void kernel_launch(void* const* d_in, const int* in_sizes, int n_in,
                              void* d_out, int out_size, void* d_ws, size_t ws_size,
                              hipStream_t stream) {
  const int* agti = (const int*)d_in[1];
  const float* gtb = (const float*)d_in[2];
  const float* prop = (const float*)d_in[3];
  unsigned char* ws = (unsigned char*)d_ws;
  float* out = (float*)d_out;

  k_prep<<<B_IMG * 8, 256, 0, stream>>>(agti, gtb, prop, ws, out);
  k_pairs<<<B_IMG * NPAIRT * 4, 256, 0, stream>>>(ws);
  k_resolve<<<B_IMG, RTHREADS, 0, stream>>>(gtb, ws, out);
}